// Round 19
// baseline (675.873 us; speedup 1.0000x reference)
//
#include <hip/hip_runtime.h>
#include <math.h>

constexpr int Bn = 8, Nn = 256, Dn = 768, Hn = 12, Kn = 128;
constexpr int Tn = Nn * Bn;      // 2048 tokens, [B,N] order
constexpr float SCALE = 0.125f;  // HD^-0.5, HD=64
constexpr float LOG2E = 1.4426950408889634f;
constexpr float NEGB = -1e9f;
constexpr float INV768 = 1.0f / 768.0f;

typedef __attribute__((ext_vector_type(8))) short bf16x8;
typedef __attribute__((ext_vector_type(4))) float f32x4;

#define MFMA16(a, b, c) __builtin_amdgcn_mfma_f32_16x16x32_bf16((a), (b), (c), 0, 0, 0)

__device__ __forceinline__ void gload_lds16(const void* g, void* l) {
  __builtin_amdgcn_global_load_lds(
      (const __attribute__((address_space(1))) void*)g,
      (__attribute__((address_space(3))) void*)l, 16, 0, 0);
}

__device__ __forceinline__ float fexp2(float x) {  // raw v_exp_f32 (D = 2^S0)
  float r;
  asm("v_exp_f32 %0, %1" : "=v"(r) : "v"(x));
  return r;
}
__device__ __forceinline__ float frcp(float x) { return __builtin_amdgcn_rcpf(x); }

__device__ __forceinline__ ushort f2bf(float x) {  // round-to-nearest-even
  union { float f; unsigned u; } v; v.f = x;
  unsigned r = (v.u + 0x7fff + ((v.u >> 16) & 1)) >> 16;
  return (ushort)r;
}
__device__ __forceinline__ ushort f2bf_t(float x) {  // truncate (1 inst)
  union { float f; unsigned u; } v; v.f = x;
  return (ushort)(v.u >> 16);
}
__device__ __forceinline__ float bf2f(ushort u) {
  union { unsigned u; float f; } v; v.u = ((unsigned)u) << 16;
  return v.f;
}
__device__ __forceinline__ unsigned pk2(float a, float b) {     // truncating pack
  return (unsigned)f2bf_t(a) | ((unsigned)f2bf_t(b) << 16);
}
__device__ __forceinline__ unsigned pk2r(float a, float b) {    // rounding pack
  return (unsigned)f2bf(a) | ((unsigned)f2bf(b) << 16);
}
// tanh-approx gelu (FFN path)
__device__ __forceinline__ float gelu_fast(float x) {
  float u = x * (0.7978845608f + 0.0356774081f * x * x);
  float e = fexp2(2.8853901f * u);      // exp(2u) = exp2(2u*log2e)
  float t = 1.0f - 2.0f * frcp(e + 1.0f);
  return 0.5f * x * (1.0f + t);
}
// sigmoid-approx gelu (bias-MLP path): x * sigmoid(1.702 x)
__device__ __forceinline__ float gelu_sig(float x) {
  return x * frcp(1.0f + fexp2(-2.4554669f * x));
}
__device__ __forceinline__ float wave_sum(float v) {
#pragma unroll
  for (int off = 32; off; off >>= 1) v += __shfl_xor(v, off);
  return v;
}

// ---------------- all weight transposes in ONE dispatch -----------------------
// segments: ap 144 | wi 1728 | wo 576 | w1 576 | w2 576 | bp 4 | ew 24 | w2pad 1
__global__ __launch_bounds__(256) void wtrans_all(
    const float* __restrict__ ap_w, const float* __restrict__ wi,
    const float* __restrict__ wo, const float* __restrict__ w1,
    const float* __restrict__ w2, const float* __restrict__ bp_w1,
    const float* __restrict__ edge_w, const float* __restrict__ bp_w2,
    ushort* __restrict__ apT, ushort* __restrict__ wiT, ushort* __restrict__ woT,
    ushort* __restrict__ w1T, ushort* __restrict__ w2T, ushort* __restrict__ w1bT,
    ushort* __restrict__ ewT, ushort* __restrict__ w2b) {
  __shared__ float tile[64][65];
  int bid = blockIdx.x;
  int tid = threadIdx.x;
  const float* W; ushort* WT; int Kd, Nd, nx;
  if (bid < 144) { W = ap_w; WT = apT; Kd = 768; Nd = 768; nx = 12; }
  else if ((bid -= 144) < 1728) {
    int z = bid / 432; bid %= 432;
    W = wi + (size_t)z * 768 * 2304; WT = wiT + (size_t)z * 768 * 2304;
    Kd = 768; Nd = 2304; nx = 36;
  }
  else if ((bid -= 1728) < 576) {
    int z = bid / 144; bid %= 144;
    W = wo + (size_t)z * 768 * 768; WT = woT + (size_t)z * 768 * 768;
    Kd = 768; Nd = 768; nx = 12;
  }
  else if ((bid -= 576) < 576) {
    int z = bid / 144; bid %= 144;
    W = w1 + (size_t)z * 768 * 768; WT = w1T + (size_t)z * 768 * 768;
    Kd = 768; Nd = 768; nx = 12;
  }
  else if ((bid -= 576) < 576) {
    int z = bid / 144; bid %= 144;
    W = w2 + (size_t)z * 768 * 768; WT = w2T + (size_t)z * 768 * 768;
    Kd = 768; Nd = 768; nx = 12;
  }
  else if ((bid -= 576) < 4) { W = bp_w1; WT = w1bT; Kd = 128; Nd = 128; nx = 2; }
  else if ((bid -= 4) < 24) { W = edge_w; WT = ewT; Kd = 128; Nd = 768; nx = 12; }
  else {
    // w2pad: bp_w2 [128,12] -> w2b [16][128] bf16, rows 12..15 zero
    for (int e = tid; e < 2048; e += 256) {
      int h = e >> 7, k = e & 127;
      w2b[e] = (h < 12) ? f2bf(bp_w2[k * 12 + h]) : (ushort)0;
    }
    return;
  }
  int n0 = (bid % nx) * 64, k0 = (bid / nx) * 64;
  for (int e = tid; e < 64 * 64; e += 256) {
    int r = e >> 6, c = e & 63;
    tile[r][c] = W[(size_t)(k0 + r) * Nd + n0 + c];
  }
  __syncthreads();
  for (int e = tid; e < 64 * 64; e += 256) {
    int r = e >> 6, c = e & 63;
    WT[(size_t)(n0 + r) * Kd + k0 + c] = f2bf(tile[c][r]);
  }
}

// ---- bias MLP + edge-feature sums, all-MFMA, one block per (b,i) ------------
// Ag is WAVE-PRIVATE; 3 barriers total. Bias stored PERMUTED (j -> (j&15)*16+(j>>4))
// and pre-multiplied by LOG2E. Gaussian cn folded into exp2 arg (log2(cn)).
__global__ __launch_bounds__(256) void gbias_kernel(
    const int* __restrict__ atoms, const float* __restrict__ pos,
    const float* __restrict__ means, const float* __restrict__ stds,
    const float* __restrict__ gmul, const float* __restrict__ gbias_,
    const ushort* __restrict__ w1T, const float* __restrict__ b1,
    const ushort* __restrict__ w2b, const float* __restrict__ b2,
    ushort* __restrict__ biasb, ushort* __restrict__ efb) {
  int i = blockIdx.x, b = blockIdx.y;
  __shared__ char W1s[32768];      // [128 n][128 k] bf16, XOR-swizzled; persists
  __shared__ char Ag[16384];       // gbf [64 j][128 k] / g [64 j][128 n] / ef partials
  __shared__ float sj[256];        // ml*dist+bs per j
  __shared__ int pml[256];
  __shared__ float b1s[128];
  const int tid = threadIdx.x, w = tid >> 6, ln = tid & 63;
  const int frow = ln & 15, fgrp = ln >> 4;
  {
    int srow = ln >> 4, sc = ln & 15;
#pragma unroll
    for (int q = 0; q < 8; ++q) {
      int inst = w * 8 + q;
      int row = inst * 4 + srow;
      const char* g = (const char*)(w1T + row * 128) + ((sc * 16) ^ ((row & 7) << 4));
      gload_lds16(g, W1s + inst * 1024);
    }
  }
  if (tid < 128) b1s[tid] = b1[tid];
  {
    int ai = atoms[b * Nn + i];
    int j = tid;
    int aj = atoms[b * Nn + j];
    float dx = pos[(b * Nn + i) * 3]     - pos[(b * Nn + j) * 3];
    float dy = pos[(b * Nn + i) * 3 + 1] - pos[(b * Nn + j) * 3 + 1];
    float dz = pos[(b * Nn + i) * 3 + 2] - pos[(b * Nn + j) * 3 + 2];
    float sq = dx * dx + dy * dy + dz * dz;
    float d = sq > 0.f ? sqrtf(sq) : 0.f;
    int et = ai * 10 + aj;
    sj[j] = fmaf(gmul[et], d, gbias_[et]);
    pml[j] = (aj == 0);
  }
  // per-thread k-pair constants (once); quadratic scaled by LOG2E; cn folded
  const int kp = tid & 63, rquad = tid >> 6;  // rquad == wave id
  const int k0i = 2 * kp, k1i = 2 * kp + 1;
  float A0, B0, C0, A1, B1, C1;
  {
    float m0 = means[k0i], m1 = means[k1i];
    float sd0 = fabsf(stds[k0i]) + 1e-5f, sd1 = fabsf(stds[k1i]) + 1e-5f;
    float i0 = 1.0f / sd0, i1 = 1.0f / sd1;
    float a0 = -0.5f * i0 * i0 * LOG2E, a1 = -0.5f * i1 * i1 * LOG2E;
    float L0 = __log2f(i0 * 0.3989423f), L1 = __log2f(i1 * 0.3989423f);
    A0 = a0; B0 = -2.0f * a0 * m0; C0 = a0 * m0 * m0 + L0;
    A1 = a1; B1 = -2.0f * a1 * m1; C1 = a1 * m1 * m1 + L1;
  }
  __syncthreads();   // barrier 1: W1s / sj / pml visible to all waves
  float facc0 = 0.f, facc1 = 0.f;   // ef partial sums (cn-scaled)

  for (int jt = 0; jt < 4; ++jt) {
    int j0 = jt * 64;
    // build Ag rows w*16..+16 (wave-private); values already cn-scaled
#pragma unroll
    for (int rr = 0; rr < 16; ++rr) {
      int row = rquad * 16 + rr;
      int jg = j0 + row;
      float s = sj[jg];
      float e0 = fexp2(fmaf(fmaf(A0, s, B0), s, C0));
      float e1 = fexp2(fmaf(fmaf(A1, s, B1), s, C1));
      int padj = pml[jg];
      facc0 += padj ? 0.f : e0;
      facc1 += padj ? 0.f : e1;
      *(unsigned*)(Ag + row * 256 + ((4 * kp) ^ ((row & 7) << 4))) = pk2(e0, e1);
    }
    // phase B: wave reads its own Ag rows (w*16+frow) + shared W1s
    f32x4 acc[8] = {};
    const int arow = w * 16 + frow;
#pragma unroll
    for (int ks = 0; ks < 4; ++ks) {
      bf16x8 af = *(const bf16x8*)(Ag + arow * 256 + ((ks * 64 + fgrp * 16) ^ ((arow & 7) << 4)));
#pragma unroll
      for (int nt = 0; nt < 8; ++nt) {
        int brow = nt * 16 + frow;
        bf16x8 bfv = *(const bf16x8*)(W1s + brow * 256 + ((ks * 64 + fgrp * 16) ^ ((brow & 7) << 4)));
        acc[nt] = MFMA16(af, bfv, acc[nt]);
      }
    }
    // gelu + store g rows w*16..+16 (wave-private)
#pragma unroll
    for (int nt = 0; nt < 8; ++nt) {
      int n = nt * 16 + frow;
#pragma unroll
      for (int r = 0; r < 4; ++r) {
        int jloc = w * 16 + fgrp * 4 + r;
        float g = gelu_sig(acc[nt][r] + b1s[n]);
        *(ushort*)(Ag + jloc * 256 + ((2 * n) ^ ((jloc & 7) << 4))) = f2bf_t(g);
      }
    }
    // phase C: wave reads its own g rows (w*16+frow); B from global w2b
    {
      f32x4 acc2 = {};
      int jrow = w * 16 + frow;
      const ushort* w2p = w2b + frow * 128;
#pragma unroll
      for (int ks = 0; ks < 4; ++ks) {
        bf16x8 af = *(const bf16x8*)(Ag + jrow * 256 + ((ks * 64 + fgrp * 16) ^ ((jrow & 7) << 4)));
        bf16x8 bfv = *(const bf16x8*)(w2p + ks * 32 + fgrp * 8);
        acc2 = MFMA16(af, bfv, acc2);
      }
      if (frow < 12) {
        float bv = b2[frow];
#pragma unroll
        for (int r = 0; r < 4; ++r) {
          int jl = w * 16 + fgrp * 4 + r;
          int jg = j0 + jl;
          float v = pml[jg] ? NEGB : (acc2[r] + bv) * LOG2E;
          int pj = ((jg & 15) << 4) | (jg >> 4);  // permuted column
          biasb[(((size_t)b * Hn + frow) * Nn + i) * Nn + pj] = f2bf(v);
        }
      }
    }
    // no barrier: next build overwrites only this wave's own rows
  }
  // ef reduction: efp scratch aliases wave-0's Ag rows -> need barriers
  __syncthreads();   // barrier 2: all waves done with Ag
  {
    float* efp = (float*)Ag;   // [64 kp][4 rquad][2]
    efp[(kp * 4 + rquad) * 2 + 0] = facc0;
    efp[(kp * 4 + rquad) * 2 + 1] = facc1;
    __syncthreads(); // barrier 3: partials visible
    if (tid < 128) {
      int k = tid, kq = k >> 1, lo = k & 1;
      float s = efp[(kq * 4 + 0) * 2 + lo] + efp[(kq * 4 + 1) * 2 + lo] +
                efp[(kq * 4 + 2) * 2 + lo] + efp[(kq * 4 + 3) * 2 + lo];
      efb[(size_t)(b * Nn + i) * Kn + k] = f2bf(s);   // cn already folded
    }
  }
}

// ---------------- generic MFMA GEMM 64x64, BK=128 -----------------------------
// MODE 0: bf16 out; 1: gelu bf16 out; 2: f32 out + residual; 3: f32 out;
// MODE 5: bf16 out + emb[atoms]-gather
template <int MODE>
__global__ __launch_bounds__(256, 4) void mgemm(
    const ushort* __restrict__ A, const ushort* __restrict__ WT,
    const float* __restrict__ bias, const float* __restrict__ res,
    void* __restrict__ Cout, const int* __restrict__ atomsp,
    const float* __restrict__ embp, int M, int Kd, int Nd) {
  __shared__ char smem[32768];
  char* ldsA = smem;           // [64 rows][128 k] bf16 swizzled (256B rows)
  char* ldsB = smem + 16384;
  const int tid = threadIdx.x, w = tid >> 6, ln = tid & 63;
  const int m0 = blockIdx.y * 64, n0 = blockIdx.x * 64;
  const int wm = (w >> 1) * 32, wn = (w & 1) * 32;
  const int srow = ln >> 4, schunk = ln & 15;   // inst covers 4 rows x 256B
  const int frow = ln & 15, fgrp = ln >> 4;
  f32x4 acc[2][2] = {};
  for (int kt = 0; kt < Kd; kt += 128) {
    __syncthreads();
#pragma unroll
    for (int q = 0; q < 4; ++q) {
      int I = w * 4 + q;
      int r = I * 4 + srow;
      gload_lds16((const char*)(A + (size_t)(m0 + r) * Kd + kt) +
                      ((schunk * 16) ^ ((r & 7) << 4)),
                  ldsA + I * 1024);
    }
#pragma unroll
    for (int q = 0; q < 4; ++q) {
      int I = w * 4 + q;
      int r = I * 4 + srow;
      gload_lds16((const char*)(WT + (size_t)(n0 + r) * Kd + kt) +
                      ((schunk * 16) ^ ((r & 7) << 4)),
                  ldsB + I * 1024);
    }
    __syncthreads();
#pragma unroll
    for (int ks = 0; ks < 4; ++ks) {
      bf16x8 af[2], bfv[2];
#pragma unroll
      for (int mt = 0; mt < 2; ++mt) {
        int row = wm + mt * 16 + frow;
        af[mt] = *(const bf16x8*)(ldsA + row * 256 + ((ks * 64 + fgrp * 16) ^ ((row & 7) << 4)));
      }
#pragma unroll
      for (int nt = 0; nt < 2; ++nt) {
        int row = wn + nt * 16 + frow;
        bfv[nt] = *(const bf16x8*)(ldsB + row * 256 + ((ks * 64 + fgrp * 16) ^ ((row & 7) << 4)));
      }
      acc[0][0] = MFMA16(af[0], bfv[0], acc[0][0]);
      acc[0][1] = MFMA16(af[0], bfv[1], acc[0][1]);
      acc[1][0] = MFMA16(af[1], bfv[0], acc[1][0]);
      acc[1][1] = MFMA16(af[1], bfv[1], acc[1][1]);
    }
  }
#pragma unroll
  for (int nt = 0; nt < 2; ++nt) {
    int n = n0 + wn + nt * 16 + frow;
    float bv = bias[n];
#pragma unroll
    for (int mt = 0; mt < 2; ++mt) {
#pragma unroll
      for (int r = 0; r < 4; ++r) {
        int m = m0 + wm + mt * 16 + fgrp * 4 + r;
        float v = acc[mt][nt][r] + bv;
        if (MODE == 1) v = gelu_fast(v);
        if (MODE == 2) v += res[(size_t)m * Nd + n];
        if (MODE == 5) v += embp[(size_t)atomsp[m] * Nd + n];
        if (MODE == 2 || MODE == 3) ((float*)Cout)[(size_t)m * Nd + n] = v;
        else                        ((ushort*)Cout)[(size_t)m * Nd + n] = f2bf(v);
      }
    }
  }
}

// ---------------- MFMA GEMM 128x128, qkv epilogue (Q pre-scaled, V->vT) ------
__global__ __launch_bounds__(256, 3) void mgemm128_qkv(
    const ushort* __restrict__ A, const ushort* __restrict__ WT,
    const float* __restrict__ bias, ushort* __restrict__ vTout,
    ushort* __restrict__ Cout, int M, int Kd, int Nd) {
  __shared__ char smem[32768];
  char* ldsA = smem;
  char* ldsB = smem + 16384;
  const int tid = threadIdx.x, w = tid >> 6, ln = tid & 63;
  const int m0 = blockIdx.y * 128, n0 = blockIdx.x * 128;
  const int wm = (w >> 1) * 64, wn = (w & 1) * 64;
  const int srow = ln >> 3, schunk = ln & 7;
  const int sswz = (schunk * 16) ^ (srow << 4);
  const int frow = ln & 15, fgrp = ln >> 4;
  f32x4 acc[4][4] = {};
  for (int kt = 0; kt < Kd; kt += 64) {
    __syncthreads();
#pragma unroll
    for (int q = 0; q < 4; ++q) {
      int r = (w * 4 + q) * 8 + srow;
      gload_lds16((const char*)(A + (size_t)(m0 + r) * Kd + kt) + sswz, ldsA + (w * 4 + q) * 1024);
    }
#pragma unroll
    for (int q = 0; q < 4; ++q) {
      int r = (w * 4 + q) * 8 + srow;
      gload_lds16((const char*)(WT + (size_t)(n0 + r) * Kd + kt) + sswz, ldsB + (w * 4 + q) * 1024);
    }
    __syncthreads();
#pragma unroll
    for (int ks = 0; ks < 2; ++ks) {
      bf16x8 af[4], bfv[4];
#pragma unroll
      for (int mt = 0; mt < 4; ++mt) {
        int row = wm + mt * 16 + frow;
        af[mt] = *(const bf16x8*)(ldsA + row * 128 + ((ks * 64 + fgrp * 16) ^ ((row & 7) << 4)));
      }
#pragma unroll
      for (int nt = 0; nt < 4; ++nt) {
        int row = wn + nt * 16 + frow;
        bfv[nt] = *(const bf16x8*)(ldsB + row * 128 + ((ks * 64 + fgrp * 16) ^ ((row & 7) << 4)));
      }
#pragma unroll
      for (int mt = 0; mt < 4; ++mt)
#pragma unroll
        for (int nt = 0; nt < 4; ++nt)
          acc[mt][nt] = MFMA16(af[mt], bfv[nt], acc[mt][nt]);
    }
  }
#pragma unroll
  for (int nt = 0; nt < 4; ++nt) {
    int n = n0 + wn + nt * 16 + frow;
    float bv = bias[n];
    if (n >= 1536) {
      int dd = n - 1536, h = dd >> 6, d = dd & 63;
#pragma unroll
      for (int mt = 0; mt < 4; ++mt) {
        int m = m0 + wm + mt * 16 + fgrp * 4;   // r=0..3 -> j consecutive
        int bb = m >> 8, j = m & 255;
        uint2 pkv;
        pkv.x = pk2r(acc[mt][nt][0] + bv, acc[mt][nt][1] + bv);
        pkv.y = pk2r(acc[mt][nt][2] + bv, acc[mt][nt][3] + bv);
        *(uint2*)&vTout[(((size_t)bb * Hn + h) * 64 + d) * 256 + j] = pkv;
      }
    } else {
      float sc = (n < 768) ? SCALE * LOG2E : 1.0f;  // Q pre-scaled for exp2 softmax
#pragma unroll
      for (int mt = 0; mt < 4; ++mt) {
#pragma unroll
        for (int r = 0; r < 4; ++r) {
          int m = m0 + wm + mt * 16 + fgrp * 4 + r;
          Cout[(size_t)m * Nd + n] = f2bf((acc[mt][nt][r] + bv) * sc);
        }
      }
    }
  }
}

// ---------------- MFMA attention: K staged, V direct from global -------------
// LDS 32KB (K + P alias) -> ~3 blocks/CU. 1D XCD-swizzled grid; tokens [B,N].
__global__ __launch_bounds__(256, 3) void attn_mfma(
    const ushort* __restrict__ qkv, const ushort* __restrict__ vT,
    const ushort* __restrict__ biasb, ushort* __restrict__ Oout) {
  // bijective XCD swizzle: 384 blocks, 8 XCDs, 48 per XCD share (b,h) runs
  int wgid = (blockIdx.x & 7) * 48 + (blockIdx.x >> 3);
  int it = wgid & 3, rest = wgid >> 2;
  int h = rest % Hn, b = rest / Hn;
  int i0 = it * 64;
  __shared__ char Ks[32768];   // [256 j][64 k] bf16 swizzled; later P[4][16][256]
  const int tid = threadIdx.x, w = tid >> 6, ln = tid & 63;
  const int frow = ln & 15, fgrp = ln >> 4;
  {
    const int srow = ln >> 3, schunk = ln & 7;
#pragma unroll
    for (int q = 0; q < 8; ++q) {
      int inst = w * 8 + q;
      int row = inst * 8 + srow;
      const char* g = (const char*)(qkv + (size_t)(b * Nn + row) * 2304 + 768 + h * 64) +
                      ((schunk * 16) ^ ((row & 7) << 4));
      gload_lds16(g, Ks + inst * 1024);
    }
  }
  bf16x8 qf[2];
  {
    int qrow = i0 + w * 16 + frow;
    const ushort* qg = qkv + (size_t)(b * Nn + qrow) * 2304 + h * 64 + fgrp * 8;
    qf[0] = *(const bf16x8*)qg;
    qf[1] = *(const bf16x8*)(qg + 32);
  }
  __syncthreads();
  f32x4 s[16];
#pragma unroll
  for (int jtl = 0; jtl < 16; ++jtl) {
    int row = jtl * 16 + frow;
    const char* kb = Ks + row * 128;
    bf16x8 k0 = *(const bf16x8*)(kb + ((fgrp * 16) ^ ((row & 7) << 4)));
    bf16x8 k1 = *(const bf16x8*)(kb + ((64 + fgrp * 16) ^ ((row & 7) << 4)));
    f32x4 t = {};
    t = MFMA16(qf[0], k0, t);
    t = MFMA16(qf[1], k1, t);
    s[jtl] = t;
  }
  // bias (permuted layout) + exp2 + sum
  float inv[4];
#pragma unroll
  for (int r = 0; r < 4; ++r) {
    int i = i0 + w * 16 + fgrp * 4 + r;
    const ushort* brow = biasb + (((size_t)b * Hn + h) * Nn + i) * Nn + frow * 16;
    bf16x8 b0 = *(const bf16x8*)brow;
    bf16x8 b1 = *(const bf16x8*)(brow + 8);
    float su = 0.f;
#pragma unroll
    for (int jtl = 0; jtl < 16; ++jtl) {
      float bv = bf2f((ushort)(jtl < 8 ? b0[jtl] : b1[jtl - 8]));
      float p = fexp2(s[jtl][r] + bv);
      s[jtl][r] = p;
      su += p;
    }
    su += __shfl_xor(su, 1); su += __shfl_xor(su, 2);
    su += __shfl_xor(su, 4); su += __shfl_xor(su, 8);
    inv[r] = frcp(su);
  }
  __syncthreads();  // all waves done reading Ks before P overwrites it
  char* Ps = Ks + w * 8192;   // wave-private 8KB
#pragma unroll
  for (int r = 0; r < 4; ++r) {
    int prow = fgrp * 4 + r;
#pragma unroll
    for (int jtl = 0; jtl < 16; ++jtl) {
      int cb = jtl * 32 + frow * 2;
      *(ushort*)(Ps + prow * 512 + (cb ^ ((prow & 7) << 4))) = f2bf_t(s[jtl][r]);
    }
  }
  // NO barrier: Ps is wave-private; intra-wave LDS ordering via lgkmcnt
  bf16x8 pf[8];
#pragma unroll
  for (int ks = 0; ks < 8; ++ks)
    pf[ks] = *(const bf16x8*)(Ps + frow * 512 + ((ks * 64 + fgrp * 16) ^ ((frow & 7) << 4)));
  // PV: V^T fragments direct from global (512B-stride rows, 16 lanes x 16B
  // contiguous per row; 8 independent loads per dt batch + overlap with MFMA)
  const ushort* vbase = vT + (size_t)((b * Hn + h) * 64) * 256 + fgrp * 8;
  f32x4 o[4] = {};
#pragma unroll
  for (int dt = 0; dt < 4; ++dt) {
    int row = dt * 16 + frow;
    const ushort* vg = vbase + (size_t)row * 256;
    bf16x8 vf[8];
#pragma unroll
    for (int ks = 0; ks < 8; ++ks) vf[ks] = *(const bf16x8*)(vg + ks * 32);
#pragma unroll
    for (int ks = 0; ks < 8; ++ks) o[dt] = MFMA16(pf[ks], vf[ks], o[dt]);
  }
#pragma unroll
  for (int dt = 0; dt < 4; ++dt)
#pragma unroll
    for (int r = 0; r < 4; ++r) {
      int i = i0 + w * 16 + fgrp * 4 + r;
      Oout[(size_t)(b * Nn + i) * Dn + h * 64 + dt * 16 + frow] = f2bf(o[dt][r] * inv[r]);
    }
}

// ---------------- LayerNorm over D=768 ---------------------------------------
// MODE 0: bf16 out [T][D]; MODE 1: f32 out [T][D]
template <int MODE>
__global__ __launch_bounds__(256) void ln_kernel(
    const float* __restrict__ x, const float* __restrict__ sc,
    const float* __restrict__ bi, void* __restrict__ out) {
  int t = blockIdx.x;
  int tid = threadIdx.x;
  const float* xr = x + (size_t)t * Dn;
  float v0 = xr[tid], v1 = xr[tid + 256], v2 = xr[tid + 512];
  __shared__ float red[4], red2[4];
  float s = wave_sum(v0 + v1 + v2);
  if ((tid & 63) == 0) red[tid >> 6] = s;
  __syncthreads();
  float mean = (red[0] + red[1] + red[2] + red[3]) * INV768;
  float d0 = v0 - mean, d1 = v1 - mean, d2 = v2 - mean;
  float vs = wave_sum(d0 * d0 + d1 * d1 + d2 * d2);
  if ((tid & 63) == 0) red2[tid >> 6] = vs;
  __syncthreads();
  float var = (red2[0] + red2[1] + red2[2] + red2[3]) * INV768;
  float r = rsqrtf(var + 1e-5f);
  if (MODE == 0) {
    ushort* o = (ushort*)out + (size_t)t * Dn;
    o[tid]       = f2bf(d0 * r * sc[tid]       + bi[tid]);
    o[tid + 256] = f2bf(d1 * r * sc[tid + 256] + bi[tid + 256]);
    o[tid + 512] = f2bf(d2 * r * sc[tid + 512] + bi[tid + 512]);
  } else {
    float* o = (float*)out + (size_t)t * Dn;
    o[tid]       = d0 * r * sc[tid]       + bi[tid];
    o[tid + 256] = d1 * r * sc[tid + 256] + bi[tid + 256];
    o[tid + 512] = d2 * r * sc[tid + 512] + bi[tid + 512];
  }
}

// =============================================================================
extern "C" void kernel_launch(void* const* d_in, const int* in_sizes, int n_in,
                              void* d_out, int out_size, void* d_ws, size_t ws_size,
                              hipStream_t stream) {
  (void)in_sizes; (void)n_in; (void)out_size; (void)ws_size;
  const int*   atoms    = (const int*)  d_in[0];
  const float* pos      = (const float*)d_in[1];
  const float* atom_emb = (const float*)d_in[2];
  const float* gbf_means= (const float*)d_in[3];
  const float* gbf_stds = (const float*)d_in[4];
  const float* gbf_mul  = (const float*)d_in[5];
  const float* gbf_bias = (const float*)d_in[6];
  const float* bp_w1    = (const float*)d_in[7];
  const float* bp_b1    = (const float*)d_in[8];
  const float* bp_w2    = (const float*)d_in[9];
  const float* bp_b2    = (const float*)d_in[10];
  const float* edge_w   = (const float*)d_in[11];
  const float* edge_b   = (const float*)d_in[12];
  const float* ap_w     = (const float*)d_in[13];
  const float* ap_b     = (const float*)d_in[14];
  const float* ln1_s    = (const float*)d_in[15];
  const float* ln1_b    = (const float*)d_in[16];
  const float* wi       = (const float*)d_in[17];
  const float* bi       = (const float*)d_in[18];
  const float* wo       = (const float*)d_in[19];
  const float* bo       = (const float*)d_in[20];
  const float* ln2_s    = (const float*)d_in[21];
  const float* ln2_b    = (const float*)d_in[22];
  const float* w1       = (const float*)d_in[23];
  const float* b1       = (const float*)d_in[24];
  const float* w2       = (const float*)d_in[25];
  const float* b2       = (const float*)d_in[26];
  const float* fln_s    = (const float*)d_in[27];
  const float* fln_b    = (const float*)d_in[28];
  float* out = (float*)d_out;

  // workspace layout (u16 units unless noted)
  ushort* wsb   = (ushort*)d_ws;
  ushort* biasb = wsb;                                  // 6291456
  ushort* qkvb  = biasb + (size_t)Bn * Hn * Nn * Nn;    // 4718592 (overlays: apT, ewT, ffnb)
  ushort* hb    = qkvb + (size_t)Tn * 2304;             // 1572864
  ushort* vT    = hb + (size_t)Tn * Dn;                 // 1572864 (efb overlays)
  ushort* wiT   = vT + (size_t)Bn * Hn * 64 * 256;      // 7077888
  ushort* woT   = wiT + (size_t)4 * 2304 * Dn;          // 2359296
  ushort* w1T   = woT + (size_t)4 * Dn * Dn;            // 2359296
  ushort* w2T   = w1T + (size_t)4 * Dn * Dn;            // 2359296
  ushort* w1bT  = w2T + (size_t)4 * Dn * Dn;            // 16384
  ushort* w2b   = w1bT + 16384;                         // 2048
  float*  xbuf  = (float*)(w2b + 2048);                 // Tn*Dn f32
  ushort* apT   = qkvb;                                 // overlay (dead before qkv GEMM)
  ushort* ewT   = qkvb + 589824;                        // overlay (dead before qkv GEMM)
  ushort* ffnb  = qkvb;                                 // overlay (qkv dead in FFN phase)
  ushort* efb   = vT;                                   // overlay (dead before layer 0)

  // all weight transposes + w2 pad in one dispatch
  wtrans_all<<<3629, 256, 0, stream>>>(ap_w, wi, wo, w1, w2, bp_w1, edge_w, bp_w2,
                                       apT, wiT, woT, w1T, w2T, w1bT, ewT, w2b);

  dim3 gridNB(Nn, Bn);
  // bias MLP + ef sums (merged, barrier-minimal)
  gbias_kernel<<<gridNB, 256, 0, stream>>>(atoms, pos, gbf_means, gbf_stds,
                                           gbf_mul, gbf_bias, w1bT, bp_b1, w2b, bp_b2,
                                           biasb, efb);
  // node = emb[atoms] + ef@edge_w + edge_b  (bf16 -> hb)
  mgemm<5><<<dim3(12, 32), 256, 0, stream>>>(efb, ewT, edge_b, nullptr, hb,
                                             atoms, atom_emb, Tn, 128, Dn);
  // x = node@ap_w + ap_b (f32 -> xbuf)
  mgemm<3><<<dim3(12, 32), 256, 0, stream>>>(hb, apT, ap_b, nullptr, xbuf,
                                             nullptr, nullptr, Tn, Dn, Dn);

  for (int it = 0; it < 8; ++it) {
    int l = it & 3;
    ln_kernel<0><<<Tn, 256, 0, stream>>>(xbuf, ln1_s + l * Dn, ln1_b + l * Dn, hb);
    mgemm128_qkv<<<dim3(18, 16), 256, 0, stream>>>(hb, wiT + (size_t)l * 2304 * Dn,
                                                   bi + l * 2304, vT, qkvb, Tn, Dn, 2304);
    attn_mfma<<<384, 256, 0, stream>>>(qkvb, vT, biasb, hb);
    mgemm<2><<<dim3(12, 32), 256, 0, stream>>>(hb, woT + (size_t)l * Dn * Dn,
                                               bo + l * Dn, xbuf, xbuf,
                                               nullptr, nullptr, Tn, Dn, Dn);
    ln_kernel<0><<<Tn, 256, 0, stream>>>(xbuf, ln2_s + l * Dn, ln2_b + l * Dn, hb);
    mgemm<1><<<dim3(12, 32), 256, 0, stream>>>(hb, w1T + (size_t)l * Dn * Dn,
                                               b1 + l * Dn, nullptr, ffnb,
                                               nullptr, nullptr, Tn, Dn, Dn);
    mgemm<2><<<dim3(12, 32), 256, 0, stream>>>(ffnb, w2T + (size_t)l * Dn * Dn,
                                               b2 + l * Dn, xbuf, xbuf,
                                               nullptr, nullptr, Tn, Dn, Dn);
  }
  ln_kernel<1><<<Tn, 256, 0, stream>>>(xbuf, fln_s, fln_b, out);
}

// Round 20
// 630.112 us; speedup vs baseline: 1.0726x; 1.0726x over previous
//
#include <hip/hip_runtime.h>
#include <math.h>

constexpr int Bn = 8, Nn = 256, Dn = 768, Hn = 12, Kn = 128;
constexpr int Tn = Nn * Bn;      // 2048 tokens, [B,N] order
constexpr float SCALE = 0.125f;  // HD^-0.5, HD=64
constexpr float LOG2E = 1.4426950408889634f;
constexpr float NEGB = -1e9f;
constexpr float INV768 = 1.0f / 768.0f;

typedef __attribute__((ext_vector_type(8))) short bf16x8;
typedef __attribute__((ext_vector_type(4))) float f32x4;

#define MFMA16(a, b, c) __builtin_amdgcn_mfma_f32_16x16x32_bf16((a), (b), (c), 0, 0, 0)

__device__ __forceinline__ void gload_lds16(const void* g, void* l) {
  __builtin_amdgcn_global_load_lds(
      (const __attribute__((address_space(1))) void*)g,
      (__attribute__((address_space(3))) void*)l, 16, 0, 0);
}

__device__ __forceinline__ float fexp2(float x) {  // raw v_exp_f32 (D = 2^S0)
  float r;
  asm("v_exp_f32 %0, %1" : "=v"(r) : "v"(x));
  return r;
}
__device__ __forceinline__ float frcp(float x) { return __builtin_amdgcn_rcpf(x); }

__device__ __forceinline__ ushort f2bf(float x) {  // round-to-nearest-even
  union { float f; unsigned u; } v; v.f = x;
  unsigned r = (v.u + 0x7fff + ((v.u >> 16) & 1)) >> 16;
  return (ushort)r;
}
__device__ __forceinline__ ushort f2bf_t(float x) {  // truncate (1 inst)
  union { float f; unsigned u; } v; v.f = x;
  return (ushort)(v.u >> 16);
}
__device__ __forceinline__ float bf2f(ushort u) {
  union { unsigned u; float f; } v; v.u = ((unsigned)u) << 16;
  return v.f;
}
__device__ __forceinline__ unsigned pk2(float a, float b) {     // truncating pack
  return (unsigned)f2bf_t(a) | ((unsigned)f2bf_t(b) << 16);
}
__device__ __forceinline__ unsigned pk2r(float a, float b) {    // rounding pack
  return (unsigned)f2bf(a) | ((unsigned)f2bf(b) << 16);
}
// tanh-approx gelu (FFN path)
__device__ __forceinline__ float gelu_fast(float x) {
  float u = x * (0.7978845608f + 0.0356774081f * x * x);
  float e = fexp2(2.8853901f * u);      // exp(2u) = exp2(2u*log2e)
  float t = 1.0f - 2.0f * frcp(e + 1.0f);
  return 0.5f * x * (1.0f + t);
}
// sigmoid-approx gelu (bias-MLP path): x * sigmoid(1.702 x)
__device__ __forceinline__ float gelu_sig(float x) {
  return x * frcp(1.0f + fexp2(-2.4554669f * x));
}
__device__ __forceinline__ float wave_sum(float v) {
#pragma unroll
  for (int off = 32; off; off >>= 1) v += __shfl_xor(v, off);
  return v;
}

// ---------------- all weight transposes in ONE dispatch -----------------------
// segments: ap 144 | wi 1728 | wo 576 | w1 576 | w2 576 | bp 4 | ew 24 | w2pad 1
__global__ __launch_bounds__(256) void wtrans_all(
    const float* __restrict__ ap_w, const float* __restrict__ wi,
    const float* __restrict__ wo, const float* __restrict__ w1,
    const float* __restrict__ w2, const float* __restrict__ bp_w1,
    const float* __restrict__ edge_w, const float* __restrict__ bp_w2,
    ushort* __restrict__ apT, ushort* __restrict__ wiT, ushort* __restrict__ woT,
    ushort* __restrict__ w1T, ushort* __restrict__ w2T, ushort* __restrict__ w1bT,
    ushort* __restrict__ ewT, ushort* __restrict__ w2b) {
  __shared__ float tile[64][65];
  int bid = blockIdx.x;
  int tid = threadIdx.x;
  const float* W; ushort* WT; int Kd, Nd, nx;
  if (bid < 144) { W = ap_w; WT = apT; Kd = 768; Nd = 768; nx = 12; }
  else if ((bid -= 144) < 1728) {
    int z = bid / 432; bid %= 432;
    W = wi + (size_t)z * 768 * 2304; WT = wiT + (size_t)z * 768 * 2304;
    Kd = 768; Nd = 2304; nx = 36;
  }
  else if ((bid -= 1728) < 576) {
    int z = bid / 144; bid %= 144;
    W = wo + (size_t)z * 768 * 768; WT = woT + (size_t)z * 768 * 768;
    Kd = 768; Nd = 768; nx = 12;
  }
  else if ((bid -= 576) < 576) {
    int z = bid / 144; bid %= 144;
    W = w1 + (size_t)z * 768 * 768; WT = w1T + (size_t)z * 768 * 768;
    Kd = 768; Nd = 768; nx = 12;
  }
  else if ((bid -= 576) < 576) {
    int z = bid / 144; bid %= 144;
    W = w2 + (size_t)z * 768 * 768; WT = w2T + (size_t)z * 768 * 768;
    Kd = 768; Nd = 768; nx = 12;
  }
  else if ((bid -= 576) < 4) { W = bp_w1; WT = w1bT; Kd = 128; Nd = 128; nx = 2; }
  else if ((bid -= 4) < 24) { W = edge_w; WT = ewT; Kd = 128; Nd = 768; nx = 12; }
  else {
    // w2pad: bp_w2 [128,12] -> w2b [16][128] bf16, rows 12..15 zero
    for (int e = tid; e < 2048; e += 256) {
      int h = e >> 7, k = e & 127;
      w2b[e] = (h < 12) ? f2bf(bp_w2[k * 12 + h]) : (ushort)0;
    }
    return;
  }
  int n0 = (bid % nx) * 64, k0 = (bid / nx) * 64;
  for (int e = tid; e < 64 * 64; e += 256) {
    int r = e >> 6, c = e & 63;
    tile[r][c] = W[(size_t)(k0 + r) * Nd + n0 + c];
  }
  __syncthreads();
  for (int e = tid; e < 64 * 64; e += 256) {
    int r = e >> 6, c = e & 63;
    WT[(size_t)(n0 + r) * Kd + k0 + c] = f2bf(tile[c][r]);
  }
}

// ---- bias MLP + edge-feature sums, all-MFMA, one block per (b,i) ------------
// Ag is WAVE-PRIVATE; 3 barriers total. Bias stored PERMUTED (j -> (j&15)*16+(j>>4))
// and pre-multiplied by LOG2E. Gaussian cn folded into exp2 arg (log2(cn)).
__global__ __launch_bounds__(256) void gbias_kernel(
    const int* __restrict__ atoms, const float* __restrict__ pos,
    const float* __restrict__ means, const float* __restrict__ stds,
    const float* __restrict__ gmul, const float* __restrict__ gbias_,
    const ushort* __restrict__ w1T, const float* __restrict__ b1,
    const ushort* __restrict__ w2b, const float* __restrict__ b2,
    ushort* __restrict__ biasb, ushort* __restrict__ efb) {
  int i = blockIdx.x, b = blockIdx.y;
  __shared__ char W1s[32768];      // [128 n][128 k] bf16, XOR-swizzled; persists
  __shared__ char Ag[16384];       // gbf [64 j][128 k] / g [64 j][128 n] / ef partials
  __shared__ float sj[256];        // ml*dist+bs per j
  __shared__ int pml[256];
  __shared__ float b1s[128];
  const int tid = threadIdx.x, w = tid >> 6, ln = tid & 63;
  const int frow = ln & 15, fgrp = ln >> 4;
  {
    int srow = ln >> 4, sc = ln & 15;
#pragma unroll
    for (int q = 0; q < 8; ++q) {
      int inst = w * 8 + q;
      int row = inst * 4 + srow;
      const char* g = (const char*)(w1T + row * 128) + ((sc * 16) ^ ((row & 7) << 4));
      gload_lds16(g, W1s + inst * 1024);
    }
  }
  if (tid < 128) b1s[tid] = b1[tid];
  {
    int ai = atoms[b * Nn + i];
    int j = tid;
    int aj = atoms[b * Nn + j];
    float dx = pos[(b * Nn + i) * 3]     - pos[(b * Nn + j) * 3];
    float dy = pos[(b * Nn + i) * 3 + 1] - pos[(b * Nn + j) * 3 + 1];
    float dz = pos[(b * Nn + i) * 3 + 2] - pos[(b * Nn + j) * 3 + 2];
    float sq = dx * dx + dy * dy + dz * dz;
    float d = sq > 0.f ? sqrtf(sq) : 0.f;
    int et = ai * 10 + aj;
    sj[j] = fmaf(gmul[et], d, gbias_[et]);
    pml[j] = (aj == 0);
  }
  // per-thread k-pair constants (once); quadratic scaled by LOG2E; cn folded
  const int kp = tid & 63, rquad = tid >> 6;  // rquad == wave id
  const int k0i = 2 * kp, k1i = 2 * kp + 1;
  float A0, B0, C0, A1, B1, C1;
  {
    float m0 = means[k0i], m1 = means[k1i];
    float sd0 = fabsf(stds[k0i]) + 1e-5f, sd1 = fabsf(stds[k1i]) + 1e-5f;
    float i0 = 1.0f / sd0, i1 = 1.0f / sd1;
    float a0 = -0.5f * i0 * i0 * LOG2E, a1 = -0.5f * i1 * i1 * LOG2E;
    float L0 = __log2f(i0 * 0.3989423f), L1 = __log2f(i1 * 0.3989423f);
    A0 = a0; B0 = -2.0f * a0 * m0; C0 = a0 * m0 * m0 + L0;
    A1 = a1; B1 = -2.0f * a1 * m1; C1 = a1 * m1 * m1 + L1;
  }
  __syncthreads();   // barrier 1: W1s / sj / pml visible to all waves
  float facc0 = 0.f, facc1 = 0.f;   // ef partial sums (cn-scaled)

  for (int jt = 0; jt < 4; ++jt) {
    int j0 = jt * 64;
    // build Ag rows w*16..+16 (wave-private); values already cn-scaled
#pragma unroll
    for (int rr = 0; rr < 16; ++rr) {
      int row = rquad * 16 + rr;
      int jg = j0 + row;
      float s = sj[jg];
      float e0 = fexp2(fmaf(fmaf(A0, s, B0), s, C0));
      float e1 = fexp2(fmaf(fmaf(A1, s, B1), s, C1));
      int padj = pml[jg];
      facc0 += padj ? 0.f : e0;
      facc1 += padj ? 0.f : e1;
      *(unsigned*)(Ag + row * 256 + ((4 * kp) ^ ((row & 7) << 4))) = pk2(e0, e1);
    }
    // phase B: wave reads its own Ag rows (w*16+frow) + shared W1s
    f32x4 acc[8] = {};
    const int arow = w * 16 + frow;
#pragma unroll
    for (int ks = 0; ks < 4; ++ks) {
      bf16x8 af = *(const bf16x8*)(Ag + arow * 256 + ((ks * 64 + fgrp * 16) ^ ((arow & 7) << 4)));
#pragma unroll
      for (int nt = 0; nt < 8; ++nt) {
        int brow = nt * 16 + frow;
        bf16x8 bfv = *(const bf16x8*)(W1s + brow * 256 + ((ks * 64 + fgrp * 16) ^ ((brow & 7) << 4)));
        acc[nt] = MFMA16(af, bfv, acc[nt]);
      }
    }
    // gelu + store g rows w*16..+16 (wave-private)
#pragma unroll
    for (int nt = 0; nt < 8; ++nt) {
      int n = nt * 16 + frow;
#pragma unroll
      for (int r = 0; r < 4; ++r) {
        int jloc = w * 16 + fgrp * 4 + r;
        float g = gelu_sig(acc[nt][r] + b1s[n]);
        *(ushort*)(Ag + jloc * 256 + ((2 * n) ^ ((jloc & 7) << 4))) = f2bf_t(g);
      }
    }
    // phase C: wave reads its own g rows (w*16+frow); B from global w2b
    {
      f32x4 acc2 = {};
      int jrow = w * 16 + frow;
      const ushort* w2p = w2b + frow * 128;
#pragma unroll
      for (int ks = 0; ks < 4; ++ks) {
        bf16x8 af = *(const bf16x8*)(Ag + jrow * 256 + ((ks * 64 + fgrp * 16) ^ ((jrow & 7) << 4)));
        bf16x8 bfv = *(const bf16x8*)(w2p + ks * 32 + fgrp * 8);
        acc2 = MFMA16(af, bfv, acc2);
      }
      if (frow < 12) {
        float bv = b2[frow];
#pragma unroll
        for (int r = 0; r < 4; ++r) {
          int jl = w * 16 + fgrp * 4 + r;
          int jg = j0 + jl;
          float v = pml[jg] ? NEGB : (acc2[r] + bv) * LOG2E;
          int pj = ((jg & 15) << 4) | (jg >> 4);  // permuted column
          biasb[(((size_t)b * Hn + frow) * Nn + i) * Nn + pj] = f2bf(v);
        }
      }
    }
    // no barrier: next build overwrites only this wave's own rows
  }
  // ef reduction: efp scratch aliases wave-0's Ag rows -> need barriers
  __syncthreads();   // barrier 2: all waves done with Ag
  {
    float* efp = (float*)Ag;   // [64 kp][4 rquad][2]
    efp[(kp * 4 + rquad) * 2 + 0] = facc0;
    efp[(kp * 4 + rquad) * 2 + 1] = facc1;
    __syncthreads(); // barrier 3: partials visible
    if (tid < 128) {
      int k = tid, kq = k >> 1, lo = k & 1;
      float s = efp[(kq * 4 + 0) * 2 + lo] + efp[(kq * 4 + 1) * 2 + lo] +
                efp[(kq * 4 + 2) * 2 + lo] + efp[(kq * 4 + 3) * 2 + lo];
      efb[(size_t)(b * Nn + i) * Kn + k] = f2bf(s);   // cn already folded
    }
  }
}

// ---------------- generic MFMA GEMM 64x64, BK=128 -----------------------------
// MODE 0: bf16 out; 1: gelu bf16 out; 2: f32 out + residual; 3: f32 out;
// MODE 5: bf16 out + emb[atoms]-gather
template <int MODE>
__global__ __launch_bounds__(256, 4) void mgemm(
    const ushort* __restrict__ A, const ushort* __restrict__ WT,
    const float* __restrict__ bias, const float* __restrict__ res,
    void* __restrict__ Cout, const int* __restrict__ atomsp,
    const float* __restrict__ embp, int M, int Kd, int Nd) {
  __shared__ char smem[32768];
  char* ldsA = smem;           // [64 rows][128 k] bf16 swizzled (256B rows)
  char* ldsB = smem + 16384;
  const int tid = threadIdx.x, w = tid >> 6, ln = tid & 63;
  const int m0 = blockIdx.y * 64, n0 = blockIdx.x * 64;
  const int wm = (w >> 1) * 32, wn = (w & 1) * 32;
  const int srow = ln >> 4, schunk = ln & 15;   // inst covers 4 rows x 256B
  const int frow = ln & 15, fgrp = ln >> 4;
  f32x4 acc[2][2] = {};
  for (int kt = 0; kt < Kd; kt += 128) {
    __syncthreads();
#pragma unroll
    for (int q = 0; q < 4; ++q) {
      int I = w * 4 + q;
      int r = I * 4 + srow;
      gload_lds16((const char*)(A + (size_t)(m0 + r) * Kd + kt) +
                      ((schunk * 16) ^ ((r & 7) << 4)),
                  ldsA + I * 1024);
    }
#pragma unroll
    for (int q = 0; q < 4; ++q) {
      int I = w * 4 + q;
      int r = I * 4 + srow;
      gload_lds16((const char*)(WT + (size_t)(n0 + r) * Kd + kt) +
                      ((schunk * 16) ^ ((r & 7) << 4)),
                  ldsB + I * 1024);
    }
    __syncthreads();
#pragma unroll
    for (int ks = 0; ks < 4; ++ks) {
      bf16x8 af[2], bfv[2];
#pragma unroll
      for (int mt = 0; mt < 2; ++mt) {
        int row = wm + mt * 16 + frow;
        af[mt] = *(const bf16x8*)(ldsA + row * 256 + ((ks * 64 + fgrp * 16) ^ ((row & 7) << 4)));
      }
#pragma unroll
      for (int nt = 0; nt < 2; ++nt) {
        int row = wn + nt * 16 + frow;
        bfv[nt] = *(const bf16x8*)(ldsB + row * 256 + ((ks * 64 + fgrp * 16) ^ ((row & 7) << 4)));
      }
      acc[0][0] = MFMA16(af[0], bfv[0], acc[0][0]);
      acc[0][1] = MFMA16(af[0], bfv[1], acc[0][1]);
      acc[1][0] = MFMA16(af[1], bfv[0], acc[1][0]);
      acc[1][1] = MFMA16(af[1], bfv[1], acc[1][1]);
    }
  }
#pragma unroll
  for (int nt = 0; nt < 2; ++nt) {
    int n = n0 + wn + nt * 16 + frow;
    float bv = bias[n];
#pragma unroll
    for (int mt = 0; mt < 2; ++mt) {
#pragma unroll
      for (int r = 0; r < 4; ++r) {
        int m = m0 + wm + mt * 16 + fgrp * 4 + r;
        float v = acc[mt][nt][r] + bv;
        if (MODE == 1) v = gelu_fast(v);
        if (MODE == 2) v += res[(size_t)m * Nd + n];
        if (MODE == 5) v += embp[(size_t)atomsp[m] * Nd + n];
        if (MODE == 2 || MODE == 3) ((float*)Cout)[(size_t)m * Nd + n] = v;
        else                        ((ushort*)Cout)[(size_t)m * Nd + n] = f2bf(v);
      }
    }
  }
}

// ---------------- MFMA GEMM 128x128, qkv epilogue (Q pre-scaled, V->vT) ------
__global__ __launch_bounds__(256, 3) void mgemm128_qkv(
    const ushort* __restrict__ A, const ushort* __restrict__ WT,
    const float* __restrict__ bias, ushort* __restrict__ vTout,
    ushort* __restrict__ Cout, int M, int Kd, int Nd) {
  __shared__ char smem[32768];
  char* ldsA = smem;
  char* ldsB = smem + 16384;
  const int tid = threadIdx.x, w = tid >> 6, ln = tid & 63;
  const int m0 = blockIdx.y * 128, n0 = blockIdx.x * 128;
  const int wm = (w >> 1) * 64, wn = (w & 1) * 64;
  const int srow = ln >> 3, schunk = ln & 7;
  const int sswz = (schunk * 16) ^ (srow << 4);
  const int frow = ln & 15, fgrp = ln >> 4;
  f32x4 acc[4][4] = {};
  for (int kt = 0; kt < Kd; kt += 64) {
    __syncthreads();
#pragma unroll
    for (int q = 0; q < 4; ++q) {
      int r = (w * 4 + q) * 8 + srow;
      gload_lds16((const char*)(A + (size_t)(m0 + r) * Kd + kt) + sswz, ldsA + (w * 4 + q) * 1024);
    }
#pragma unroll
    for (int q = 0; q < 4; ++q) {
      int r = (w * 4 + q) * 8 + srow;
      gload_lds16((const char*)(WT + (size_t)(n0 + r) * Kd + kt) + sswz, ldsB + (w * 4 + q) * 1024);
    }
    __syncthreads();
#pragma unroll
    for (int ks = 0; ks < 2; ++ks) {
      bf16x8 af[4], bfv[4];
#pragma unroll
      for (int mt = 0; mt < 4; ++mt) {
        int row = wm + mt * 16 + frow;
        af[mt] = *(const bf16x8*)(ldsA + row * 128 + ((ks * 64 + fgrp * 16) ^ ((row & 7) << 4)));
      }
#pragma unroll
      for (int nt = 0; nt < 4; ++nt) {
        int row = wn + nt * 16 + frow;
        bfv[nt] = *(const bf16x8*)(ldsB + row * 128 + ((ks * 64 + fgrp * 16) ^ ((row & 7) << 4)));
      }
#pragma unroll
      for (int mt = 0; mt < 4; ++mt)
#pragma unroll
        for (int nt = 0; nt < 4; ++nt)
          acc[mt][nt] = MFMA16(af[mt], bfv[nt], acc[mt][nt]);
    }
  }
#pragma unroll
  for (int nt = 0; nt < 4; ++nt) {
    int n = n0 + wn + nt * 16 + frow;
    float bv = bias[n];
    if (n >= 1536) {
      int dd = n - 1536, h = dd >> 6, d = dd & 63;
#pragma unroll
      for (int mt = 0; mt < 4; ++mt) {
        int m = m0 + wm + mt * 16 + fgrp * 4;   // r=0..3 -> j consecutive
        int bb = m >> 8, j = m & 255;
        uint2 pkv;
        pkv.x = pk2r(acc[mt][nt][0] + bv, acc[mt][nt][1] + bv);
        pkv.y = pk2r(acc[mt][nt][2] + bv, acc[mt][nt][3] + bv);
        *(uint2*)&vTout[(((size_t)bb * Hn + h) * 64 + d) * 256 + j] = pkv;
      }
    } else {
      float sc = (n < 768) ? SCALE * LOG2E : 1.0f;  // Q pre-scaled for exp2 softmax
#pragma unroll
      for (int mt = 0; mt < 4; ++mt) {
#pragma unroll
        for (int r = 0; r < 4; ++r) {
          int m = m0 + wm + mt * 16 + fgrp * 4 + r;
          Cout[(size_t)m * Nd + n] = f2bf((acc[mt][nt][r] + bv) * sc);
        }
      }
    }
  }
}

// ---------------- MFMA attention: 1D XCD-swizzled grid; tokens [B,N] ---------
__global__ __launch_bounds__(256, 2) void attn_mfma(
    const ushort* __restrict__ qkv, const ushort* __restrict__ vT,
    const ushort* __restrict__ biasb, ushort* __restrict__ Oout) {
  // bijective XCD swizzle: 384 blocks, 8 XCDs, 48 per XCD share (b,h) runs
  int wgid = (blockIdx.x & 7) * 48 + (blockIdx.x >> 3);
  int it = wgid & 3, rest = wgid >> 2;
  int h = rest % Hn, b = rest / Hn;
  int i0 = it * 64;
  __shared__ char smem[65536];
  char* Ks = smem;           // [256 j][64 k] bf16 swizzled; later P[4][16][256]
  char* Vs = smem + 32768;   // [64 d][256 j] bf16 swizzled (V^T)
  const int tid = threadIdx.x, w = tid >> 6, ln = tid & 63;
  const int frow = ln & 15, fgrp = ln >> 4;
  {
    const int srow = ln >> 3, schunk = ln & 7;
#pragma unroll
    for (int q = 0; q < 8; ++q) {
      int inst = w * 8 + q;
      int row = inst * 8 + srow;
      const char* g = (const char*)(qkv + (size_t)(b * Nn + row) * 2304 + 768 + h * 64) +
                      ((schunk * 16) ^ ((row & 7) << 4));
      gload_lds16(g, Ks + inst * 1024);
    }
#pragma unroll
    for (int q = 0; q < 8; ++q) {
      int inst = w * 8 + q;
      int row = inst * 2 + (ln >> 5);
      int cb = (ln & 31) * 16;
      const char* g = (const char*)(vT + (size_t)((b * Hn + h) * 64 + row) * 256) +
                      (cb ^ ((row & 7) << 4));
      gload_lds16(g, Vs + inst * 1024);
    }
  }
  bf16x8 qf[2];
  {
    int qrow = i0 + w * 16 + frow;
    const ushort* qg = qkv + (size_t)(b * Nn + qrow) * 2304 + h * 64 + fgrp * 8;
    qf[0] = *(const bf16x8*)qg;
    qf[1] = *(const bf16x8*)(qg + 32);
  }
  __syncthreads();
  f32x4 s[16];
#pragma unroll
  for (int jtl = 0; jtl < 16; ++jtl) {
    int row = jtl * 16 + frow;
    const char* kb = Ks + row * 128;
    bf16x8 k0 = *(const bf16x8*)(kb + ((fgrp * 16) ^ ((row & 7) << 4)));
    bf16x8 k1 = *(const bf16x8*)(kb + ((64 + fgrp * 16) ^ ((row & 7) << 4)));
    f32x4 t = {};
    t = MFMA16(qf[0], k0, t);
    t = MFMA16(qf[1], k1, t);
    s[jtl] = t;
  }
  // bias (permuted layout) + exp2 + sum
  float inv[4];
#pragma unroll
  for (int r = 0; r < 4; ++r) {
    int i = i0 + w * 16 + fgrp * 4 + r;
    const ushort* brow = biasb + (((size_t)b * Hn + h) * Nn + i) * Nn + frow * 16;
    bf16x8 b0 = *(const bf16x8*)brow;
    bf16x8 b1 = *(const bf16x8*)(brow + 8);
    float su = 0.f;
#pragma unroll
    for (int jtl = 0; jtl < 16; ++jtl) {
      float bv = bf2f((ushort)(jtl < 8 ? b0[jtl] : b1[jtl - 8]));
      float p = fexp2(s[jtl][r] + bv);
      s[jtl][r] = p;
      su += p;
    }
    su += __shfl_xor(su, 1); su += __shfl_xor(su, 2);
    su += __shfl_xor(su, 4); su += __shfl_xor(su, 8);
    inv[r] = frcp(su);
  }
  __syncthreads();  // all waves done reading Ks before P overwrites it
  char* Ps = Ks + w * 8192;   // wave-private 8KB
#pragma unroll
  for (int r = 0; r < 4; ++r) {
    int prow = fgrp * 4 + r;
#pragma unroll
    for (int jtl = 0; jtl < 16; ++jtl) {
      int cb = jtl * 32 + frow * 2;
      *(ushort*)(Ps + prow * 512 + (cb ^ ((prow & 7) << 4))) = f2bf_t(s[jtl][r]);
    }
  }
  // NO barrier: Ps is wave-private; intra-wave LDS ordering via lgkmcnt
  bf16x8 pf[8];
#pragma unroll
  for (int ks = 0; ks < 8; ++ks)
    pf[ks] = *(const bf16x8*)(Ps + frow * 512 + ((ks * 64 + fgrp * 16) ^ ((frow & 7) << 4)));
  f32x4 o[4] = {};
#pragma unroll
  for (int dt = 0; dt < 4; ++dt) {
#pragma unroll
    for (int ks = 0; ks < 8; ++ks) {
      int row = dt * 16 + frow;
      bf16x8 vf = *(const bf16x8*)(Vs + row * 512 + ((ks * 64 + fgrp * 16) ^ ((row & 7) << 4)));
      o[dt] = MFMA16(pf[ks], vf, o[dt]);
    }
  }
#pragma unroll
  for (int dt = 0; dt < 4; ++dt)
#pragma unroll
    for (int r = 0; r < 4; ++r) {
      int i = i0 + w * 16 + fgrp * 4 + r;
      Oout[(size_t)(b * Nn + i) * Dn + h * 64 + dt * 16 + frow] = f2bf(o[dt][r] * inv[r]);
    }
}

// ---------------- LayerNorm over D=768 ---------------------------------------
// MODE 0: bf16 out [T][D]; MODE 1: f32 out [T][D]
template <int MODE>
__global__ __launch_bounds__(256) void ln_kernel(
    const float* __restrict__ x, const float* __restrict__ sc,
    const float* __restrict__ bi, void* __restrict__ out) {
  int t = blockIdx.x;
  int tid = threadIdx.x;
  const float* xr = x + (size_t)t * Dn;
  float v0 = xr[tid], v1 = xr[tid + 256], v2 = xr[tid + 512];
  __shared__ float red[4], red2[4];
  float s = wave_sum(v0 + v1 + v2);
  if ((tid & 63) == 0) red[tid >> 6] = s;
  __syncthreads();
  float mean = (red[0] + red[1] + red[2] + red[3]) * INV768;
  float d0 = v0 - mean, d1 = v1 - mean, d2 = v2 - mean;
  float vs = wave_sum(d0 * d0 + d1 * d1 + d2 * d2);
  if ((tid & 63) == 0) red2[tid >> 6] = vs;
  __syncthreads();
  float var = (red2[0] + red2[1] + red2[2] + red2[3]) * INV768;
  float r = rsqrtf(var + 1e-5f);
  if (MODE == 0) {
    ushort* o = (ushort*)out + (size_t)t * Dn;
    o[tid]       = f2bf(d0 * r * sc[tid]       + bi[tid]);
    o[tid + 256] = f2bf(d1 * r * sc[tid + 256] + bi[tid + 256]);
    o[tid + 512] = f2bf(d2 * r * sc[tid + 512] + bi[tid + 512]);
  } else {
    float* o = (float*)out + (size_t)t * Dn;
    o[tid]       = d0 * r * sc[tid]       + bi[tid];
    o[tid + 256] = d1 * r * sc[tid + 256] + bi[tid + 256];
    o[tid + 512] = d2 * r * sc[tid + 512] + bi[tid + 512];
  }
}

// =============================================================================
extern "C" void kernel_launch(void* const* d_in, const int* in_sizes, int n_in,
                              void* d_out, int out_size, void* d_ws, size_t ws_size,
                              hipStream_t stream) {
  (void)in_sizes; (void)n_in; (void)out_size; (void)ws_size;
  const int*   atoms    = (const int*)  d_in[0];
  const float* pos      = (const float*)d_in[1];
  const float* atom_emb = (const float*)d_in[2];
  const float* gbf_means= (const float*)d_in[3];
  const float* gbf_stds = (const float*)d_in[4];
  const float* gbf_mul  = (const float*)d_in[5];
  const float* gbf_bias = (const float*)d_in[6];
  const float* bp_w1    = (const float*)d_in[7];
  const float* bp_b1    = (const float*)d_in[8];
  const float* bp_w2    = (const float*)d_in[9];
  const float* bp_b2    = (const float*)d_in[10];
  const float* edge_w   = (const float*)d_in[11];
  const float* edge_b   = (const float*)d_in[12];
  const float* ap_w     = (const float*)d_in[13];
  const float* ap_b     = (const float*)d_in[14];
  const float* ln1_s    = (const float*)d_in[15];
  const float* ln1_b    = (const float*)d_in[16];
  const float* wi       = (const float*)d_in[17];
  const float* bi       = (const float*)d_in[18];
  const float* wo       = (const float*)d_in[19];
  const float* bo       = (const float*)d_in[20];
  const float* ln2_s    = (const float*)d_in[21];
  const float* ln2_b    = (const float*)d_in[22];
  const float* w1       = (const float*)d_in[23];
  const float* b1       = (const float*)d_in[24];
  const float* w2       = (const float*)d_in[25];
  const float* b2       = (const float*)d_in[26];
  const float* fln_s    = (const float*)d_in[27];
  const float* fln_b    = (const float*)d_in[28];
  float* out = (float*)d_out;

  // workspace layout (u16 units unless noted)
  ushort* wsb   = (ushort*)d_ws;
  ushort* biasb = wsb;                                  // 6291456
  ushort* qkvb  = biasb + (size_t)Bn * Hn * Nn * Nn;    // 4718592 (overlays: apT, ewT, ffnb)
  ushort* hb    = qkvb + (size_t)Tn * 2304;             // 1572864
  ushort* vT    = hb + (size_t)Tn * Dn;                 // 1572864 (efb overlays)
  ushort* wiT   = vT + (size_t)Bn * Hn * 64 * 256;      // 7077888
  ushort* woT   = wiT + (size_t)4 * 2304 * Dn;          // 2359296
  ushort* w1T   = woT + (size_t)4 * Dn * Dn;            // 2359296
  ushort* w2T   = w1T + (size_t)4 * Dn * Dn;            // 2359296
  ushort* w1bT  = w2T + (size_t)4 * Dn * Dn;            // 16384
  ushort* w2b   = w1bT + 16384;                         // 2048
  float*  xbuf  = (float*)(w2b + 2048);                 // Tn*Dn f32
  ushort* apT   = qkvb;                                 // overlay (dead before qkv GEMM)
  ushort* ewT   = qkvb + 589824;                        // overlay (dead before qkv GEMM)
  ushort* ffnb  = qkvb;                                 // overlay (qkv dead in FFN phase)
  ushort* efb   = vT;                                   // overlay (dead before layer 0)

  // all weight transposes + w2 pad in one dispatch
  wtrans_all<<<3629, 256, 0, stream>>>(ap_w, wi, wo, w1, w2, bp_w1, edge_w, bp_w2,
                                       apT, wiT, woT, w1T, w2T, w1bT, ewT, w2b);

  dim3 gridNB(Nn, Bn);
  // bias MLP + ef sums (merged, barrier-minimal)
  gbias_kernel<<<gridNB, 256, 0, stream>>>(atoms, pos, gbf_means, gbf_stds,
                                           gbf_mul, gbf_bias, w1bT, bp_b1, w2b, bp_b2,
                                           biasb, efb);
  // node = emb[atoms] + ef@edge_w + edge_b  (bf16 -> hb)
  mgemm<5><<<dim3(12, 32), 256, 0, stream>>>(efb, ewT, edge_b, nullptr, hb,
                                             atoms, atom_emb, Tn, 128, Dn);
  // x = node@ap_w + ap_b (f32 -> xbuf)
  mgemm<3><<<dim3(12, 32), 256, 0, stream>>>(hb, apT, ap_b, nullptr, xbuf,
                                             nullptr, nullptr, Tn, Dn, Dn);

  for (int it = 0; it < 8; ++it) {
    int l = it & 3;
    ln_kernel<0><<<Tn, 256, 0, stream>>>(xbuf, ln1_s + l * Dn, ln1_b + l * Dn, hb);
    mgemm128_qkv<<<dim3(18, 16), 256, 0, stream>>>(hb, wiT + (size_t)l * 2304 * Dn,
                                                   bi + l * 2304, vT, qkvb, Tn, Dn, 2304);
    attn_mfma<<<384, 256, 0, stream>>>(qkvb, vT, biasb, hb);
    mgemm<2><<<dim3(12, 32), 256, 0, stream>>>(hb, woT + (size_t)l * Dn * Dn,
                                               bo + l * Dn, xbuf, xbuf,
                                               nullptr, nullptr, Tn, Dn, Dn);
    ln_kernel<0><<<Tn, 256, 0, stream>>>(xbuf, ln2_s + l * Dn, ln2_b + l * Dn, hb);
    mgemm<1><<<dim3(12, 32), 256, 0, stream>>>(hb, w1T + (size_t)l * Dn * Dn,
                                               b1 + l * Dn, nullptr, ffnb,
                                               nullptr, nullptr, Tn, Dn, Dn);
    mgemm<2><<<dim3(12, 32), 256, 0, stream>>>(ffnb, w2T + (size_t)l * Dn * Dn,
                                               b2 + l * Dn, xbuf, xbuf,
                                               nullptr, nullptr, Tn, Dn, Dn);
  }
  ln_kernel<1><<<Tn, 256, 0, stream>>>(xbuf, fln_s, fln_b, out);
}